// Round 2
// baseline (2122.074 us; speedup 1.0000x reference)
//
#include <hip/hip_runtime.h>
#include <hip/hip_bf16.h>

#define BSZ 4
#define SEQ 2048
#define DMODEL 1024
#define DINNER 2048
#define DSTATE 64
#define NH 32
#define HD 64
#define CKL 64            // chunk length
#define NCH 32            // chunks per sequence
#define CONVD 2176
#define DPROJ 4256
#define N1 4224           // GEMM1 N = DINNER + CONVD = 33*128 (dt cols handled separately)
#define MTOT 8192         // BSZ*SEQ
#define LSTR 68           // LDS row stride (floats): 68*4 = 272 B = 17*16 -> conflict-free & 16B-aligned rows

typedef __hip_bfloat16 bf16;
typedef __attribute__((ext_vector_type(8))) short short8;   // 8 bf16 (4 VGPRs)
typedef __attribute__((ext_vector_type(4))) float f32x4;

__device__ __forceinline__ float sigmoidf_(float x) { return 1.0f / (1.0f + __expf(-x)); }

__device__ __forceinline__ void gl_lds16(const bf16* g, bf16* l) {
    __builtin_amdgcn_global_load_lds((const __attribute__((address_space(1))) void*)g,
                                     (__attribute__((address_space(3))) void*)l, 16, 0, 0);
}

__device__ __forceinline__ void store_val(float* p, float v) { *p = v; }
__device__ __forceinline__ void store_val(bf16* p, float v) { *p = __float2bfloat16(v); }

// ---------------- fp32 -> bf16 convert ----------------
__global__ void k_cvt(const float* __restrict__ src, bf16* __restrict__ dst, int n) {
    int i = blockIdx.x * 256 + threadIdx.x;
    if (i < n) dst[i] = __float2bfloat16(src[i]);
}

// ---------------- bf16 MFMA GEMM: C[M][N] = A[M][K] * W[N][K]^T ----------------
// 128x128 tile / 256-thread block, BK=32, global_load_lds width-16 staging (m97 structure).
template <typename TOUT>
__global__ __launch_bounds__(256) void k_gemm_bt(const bf16* __restrict__ A, const bf16* __restrict__ W,
                                                 TOUT* __restrict__ C, int N, int K) {
    __shared__ __align__(16) bf16 lA[128 * 32];
    __shared__ __align__(16) bf16 lB[128 * 32];
    const int tid = threadIdx.x;
    const int lane = tid & 63, w = tid >> 6;
    const int wm = w >> 1, wn = w & 1;
    const int lr = lane & 15, lk = lane >> 4;
    const int m0 = blockIdx.y * 128, n0 = blockIdx.x * 128;

    f32x4 acc[4][4];
#pragma unroll
    for (int i = 0; i < 4; i++)
#pragma unroll
        for (int j = 0; j < 4; j++) acc[i][j] = (f32x4){0.f, 0.f, 0.f, 0.f};

    const int r = tid >> 2;
    const int cs = (tid & 3) * 8;
    const bf16* ga = A + (size_t)(m0 + r) * K + cs;
    const bf16* gb = W + (size_t)(n0 + r) * K + cs;
    bf16* la0 = lA + tid * 8;   // wave-uniform base + lane*16B: contiguous in lane order
    bf16* lb0 = lB + tid * 8;

    for (int kt = 0; kt < K; kt += 32) {
        gl_lds16(ga + kt, la0);
        gl_lds16(ga + kt + (size_t)64 * K, la0 + 64 * 32);
        gl_lds16(gb + kt, lb0);
        gl_lds16(gb + kt + (size_t)64 * K, lb0 + 64 * 32);
        __syncthreads();   // compiler emits s_waitcnt vmcnt(0) before barrier
        short8 af[4], bfr[4];
#pragma unroll
        for (int im = 0; im < 4; im++)
            af[im] = *(const short8*)&lA[(wm * 64 + im * 16 + lr) * 32 + lk * 8];
#pragma unroll
        for (int jn = 0; jn < 4; jn++)
            bfr[jn] = *(const short8*)&lB[(wn * 64 + jn * 16 + lr) * 32 + lk * 8];
#pragma unroll
        for (int im = 0; im < 4; im++)
#pragma unroll
            for (int jn = 0; jn < 4; jn++)
                acc[im][jn] = __builtin_amdgcn_mfma_f32_16x16x32_bf16(af[im], bfr[jn], acc[im][jn], 0, 0, 0);
        __syncthreads();
    }
#pragma unroll
    for (int im = 0; im < 4; im++) {
        int row = m0 + wm * 64 + im * 16 + lk * 4;
#pragma unroll
        for (int jn = 0; jn < 4; jn++) {
            int col = n0 + wn * 64 + jn * 16 + lr;
            TOUT* cp = C + (size_t)row * N + col;
#pragma unroll
            for (int rr = 0; rr < 4; rr++) store_val(cp + (size_t)rr * N, acc[im][jn][rr]);
        }
    }
}

// ---------------- dt projection (fp32): dt[t][h] = softplus(u[t,:]·W_in[4224+h,:] + bias[h]) ----------
__global__ __launch_bounds__(256) void k_dtproj(const float* __restrict__ u, const float* __restrict__ W_in,
                                                const float* __restrict__ dt_bias, float* __restrict__ dtb) {
    const int t = blockIdx.x;
    const int h = threadIdx.x >> 3, sub = threadIdx.x & 7;
    const float* ur = u + (size_t)t * DMODEL;
    const float* wr = W_in + (size_t)(DPROJ - NH + h) * DMODEL;
    float s = 0.f;
    for (int k = sub * 4; k < DMODEL; k += 32)
        s += ur[k] * wr[k] + ur[k + 1] * wr[k + 1] + ur[k + 2] * wr[k + 2] + ur[k + 3] * wr[k + 3];
    s += __shfl_down(s, 4, 8);
    s += __shfl_down(s, 2, 8);
    s += __shfl_down(s, 1, 8);
    if (sub == 0) {
        float x = s + dt_bias[h];
        dtb[(size_t)t * NH + h] = (x > 20.f) ? x : log1pf(__expf(x));
    }
}

// ---------------- depthwise causal conv (width 4) + bias + SiLU ----------------
__global__ void k_conv(const bf16* __restrict__ zx, const float* __restrict__ cw,
                       const float* __restrict__ cb, bf16* __restrict__ xbc) {
    int i = blockIdx.x * 256 + threadIdx.x;
    if (i >= MTOT * CONVD) return;
    int c = i % CONVD;
    int t = i / CONVD;          // global row (b*SEQ + s)
    int s = t & (SEQ - 1);
    float acc = cb[c];
    const bf16* base = zx + (size_t)t * N1 + DINNER + c;
#pragma unroll
    for (int k = 0; k < 4; k++) {
        int st = s - 3 + k;
        if (st >= 0) acc += __bfloat162float(base[(long)(k - 3) * N1]) * cw[c * 4 + k];
    }
    xbc[i] = __float2bfloat16(acc * sigmoidf_(acc));
}

// ---------------- per-(b,c,h): chunk state S[p][n] = sum_l exp(tot-Ac[l])*dt[l]*B[l][n]*x[l][p] --------
__global__ __launch_bounds__(256) void k_cstate(const bf16* __restrict__ xbc, const float* __restrict__ dt,
                                                const float* __restrict__ A_log, bf16* __restrict__ states,
                                                float* __restrict__ totdec) {
    __shared__ __align__(16) float Bs[CKL * LSTR];
    __shared__ __align__(16) float Xs[CKL * LSTR];
    __shared__ float sdt[CKL], sAc[CKL];
    const int h = blockIdx.x, c = blockIdx.y, b = blockIdx.z;
    const int tid = threadIdx.x;
    const int row0 = b * SEQ + c * CKL;
    const float Ah = -__expf(A_log[h]);

    if (tid < 64) {  // wave 0: load dt, inclusive scan of A*dt
        float dv = dt[(size_t)(row0 + tid) * NH + h];
        sdt[tid] = dv;
        float v = Ah * dv;
#pragma unroll
        for (int d = 1; d < 64; d <<= 1) {
            float o = __shfl_up(v, d);
            if (tid >= d) v += o;
        }
        sAc[tid] = v;
    }
#pragma unroll
    for (int it = 0; it < 16; it++) {
        int idx = it * 256 + tid;
        int l = idx >> 6, n = idx & 63;
        const bf16* rp = xbc + (size_t)(row0 + l) * CONVD;
        Bs[l * LSTR + n] = __bfloat162float(rp[DINNER + n]);
        Xs[l * LSTR + n] = __bfloat162float(rp[h * HD + n]);
    }
    __syncthreads();
    const float tot = sAc[63];
    if (tid == 0) totdec[(b * NCH + c) * NH + h] = tot;
#pragma unroll
    for (int it = 0; it < 16; it++) {
        int idx = it * 256 + tid;
        int l = idx >> 6, n = idx & 63;
        Bs[l * LSTR + n] *= __expf(tot - sAc[l]) * sdt[l];
    }
    __syncthreads();
    const int p0 = (tid >> 4) * 4, n0 = (tid & 15) * 4;
    float acc[4][4] = {};
    for (int l = 0; l < CKL; l++) {
        f32x4 xv = *(const f32x4*)&Xs[l * LSTR + p0];
        f32x4 bv = *(const f32x4*)&Bs[l * LSTR + n0];
#pragma unroll
        for (int i = 0; i < 4; i++)
#pragma unroll
            for (int j = 0; j < 4; j++) acc[i][j] += xv[i] * bv[j];
    }
    bf16* sp = states + (((size_t)(b * NCH + c) * NH + h) << 12);
#pragma unroll
    for (int i = 0; i < 4; i++)
#pragma unroll
        for (int j = 0; j < 4; j++) sp[(p0 + i) * 64 + n0 + j] = __float2bfloat16(acc[i][j]);
}

// ---------------- inter-chunk scan: thread per (b,h,p,n); in-place states -> state-at-chunk-start ----
__global__ void k_scan(bf16* __restrict__ states, const float* __restrict__ totdec) {
    int i = blockIdx.x * 256 + threadIdx.x;
    if (i >= BSZ * NH * HD * DSTATE) return;
    int pn = i & 4095;
    int h = (i >> 12) & 31;
    int b = i >> 17;
    float s = 0.f;
    size_t strideC = (size_t)NH << 12;
    size_t off = (((size_t)(b * NCH) * NH + h) << 12) + pn;
    for (int c = 0; c < NCH; c++) {
        float v = __bfloat162float(states[off]);
        states[off] = __float2bfloat16(s);
        s = s * __expf(totdec[(b * NCH + c) * NH + h]) + v;
        off += strideC;
    }
}

// ---------------- per-(b,c,h): Y = Y_diag + Y_off + D*x, gate with silu(z), in-place into zx --------
__global__ __launch_bounds__(256) void k_y(const bf16* __restrict__ xbc, const float* __restrict__ dt,
                                           const float* __restrict__ A_log, const float* __restrict__ Dp,
                                           const bf16* __restrict__ states, bf16* __restrict__ zx) {
    __shared__ __align__(16) float Cs[CKL * LSTR];
    __shared__ __align__(16) float Bs[CKL * LSTR];   // S0, then B, then G
    __shared__ __align__(16) float Xs[CKL * LSTR];
    __shared__ float sdt[CKL], sAc[CKL];
    const int h = blockIdx.x, c = blockIdx.y, b = blockIdx.z;
    const int tid = threadIdx.x;
    const int row0 = b * SEQ + c * CKL;
    const float Ah = -__expf(A_log[h]);
    const float Dh = Dp[h];

    if (tid < 64) {
        float dv = dt[(size_t)(row0 + tid) * NH + h];
        sdt[tid] = dv;
        float v = Ah * dv;
#pragma unroll
        for (int d = 1; d < 64; d <<= 1) {
            float o = __shfl_up(v, d);
            if (tid >= d) v += o;
        }
        sAc[tid] = v;
    }
    const bf16* spg = states + (((size_t)(b * NCH + c) * NH + h) << 12);
#pragma unroll
    for (int it = 0; it < 16; it++) {
        int idx = it * 256 + tid;
        int l = idx >> 6, n = idx & 63;
        const bf16* rp = xbc + (size_t)(row0 + l) * CONVD;
        Cs[l * LSTR + n] = __bfloat162float(rp[DINNER + DSTATE + n]);
        Xs[l * LSTR + n] = __bfloat162float(rp[h * HD + n]);
        Bs[l * LSTR + n] = __bfloat162float(spg[idx]);   // S0[p][n]
    }
    __syncthreads();

    const int l0 = (tid >> 4) * 4, q0 = (tid & 15) * 4;   // q = p (output col) or s (G col)
    float Y[4][4];
    {   // Y_off = exp(Ac[l]) * sum_n C[l][n]*S0[p][n]  (+ D*x)
        float accv[4][4] = {};
        for (int n4 = 0; n4 < 16; n4++) {
            f32x4 cv[4], sv[4];
#pragma unroll
            for (int i = 0; i < 4; i++) cv[i] = *(const f32x4*)&Cs[(l0 + i) * LSTR + n4 * 4];
#pragma unroll
            for (int j = 0; j < 4; j++) sv[j] = *(const f32x4*)&Bs[(q0 + j) * LSTR + n4 * 4];
#pragma unroll
            for (int i = 0; i < 4; i++)
#pragma unroll
                for (int j = 0; j < 4; j++)
                    accv[i][j] += cv[i][0] * sv[j][0] + cv[i][1] * sv[j][1] +
                                  cv[i][2] * sv[j][2] + cv[i][3] * sv[j][3];
        }
#pragma unroll
        for (int i = 0; i < 4; i++) {
            float e = __expf(sAc[l0 + i]);
#pragma unroll
            for (int j = 0; j < 4; j++)
                Y[i][j] = accv[i][j] * e + Dh * Xs[(l0 + i) * LSTR + q0 + j];
        }
    }
    __syncthreads();
#pragma unroll
    for (int it = 0; it < 16; it++) {   // overwrite Bs with B
        int idx = it * 256 + tid;
        int l = idx >> 6, n = idx & 63;
        Bs[l * LSTR + n] = __bfloat162float(xbc[(size_t)(row0 + l) * CONVD + DINNER + n]);
    }
    __syncthreads();
    float G[4][4] = {};
    for (int n4 = 0; n4 < 16; n4++) {
        f32x4 cv[4], bv[4];
#pragma unroll
        for (int i = 0; i < 4; i++) cv[i] = *(const f32x4*)&Cs[(l0 + i) * LSTR + n4 * 4];
#pragma unroll
        for (int j = 0; j < 4; j++) bv[j] = *(const f32x4*)&Bs[(q0 + j) * LSTR + n4 * 4];
#pragma unroll
        for (int i = 0; i < 4; i++)
#pragma unroll
            for (int j = 0; j < 4; j++)
                G[i][j] += cv[i][0] * bv[j][0] + cv[i][1] * bv[j][1] +
                           cv[i][2] * bv[j][2] + cv[i][3] * bv[j][3];
    }
#pragma unroll
    for (int i = 0; i < 4; i++)
#pragma unroll
        for (int j = 0; j < 4; j++) {
            int l = l0 + i, s = q0 + j;
            G[i][j] = (s <= l) ? G[i][j] * __expf(sAc[l] - sAc[s]) * sdt[s] : 0.f;
        }
    __syncthreads();
#pragma unroll
    for (int i = 0; i < 4; i++)
#pragma unroll
        for (int j = 0; j < 4; j++) Bs[(l0 + i) * LSTR + q0 + j] = G[i][j];
    __syncthreads();
    // Y_diag: Y[i][j] += sum_s G[l0+i][s] * x[s][q0+j]
    for (int s4 = 0; s4 < 16; s4++) {
        f32x4 g4[4], xv[4];
#pragma unroll
        for (int i = 0; i < 4; i++) g4[i] = *(const f32x4*)&Bs[(l0 + i) * LSTR + s4 * 4];
#pragma unroll
        for (int k = 0; k < 4; k++) xv[k] = *(const f32x4*)&Xs[(s4 * 4 + k) * LSTR + q0];
#pragma unroll
        for (int i = 0; i < 4; i++)
#pragma unroll
            for (int k = 0; k < 4; k++)
#pragma unroll
                for (int j = 0; j < 4; j++) Y[i][j] += g4[i][k] * xv[k][j];
    }
    // gate with silu(z), write in-place into zx cols [h*64, h*64+64)
#pragma unroll
    for (int i = 0; i < 4; i++) {
        int t = row0 + l0 + i;
#pragma unroll
        for (int j = 0; j < 4; j++) {
            int col = h * HD + q0 + j;
            float z = __bfloat162float(zx[(size_t)t * N1 + col]);
            zx[(size_t)t * N1 + col] = __float2bfloat16(Y[i][j] * (z * sigmoidf_(z)));
        }
    }
}

// ---------------- RMSNorm over DINNER + bf16 cast for GEMM2 ----------------
__global__ __launch_bounds__(256) void k_norm(const bf16* __restrict__ zx, const float* __restrict__ nw,
                                              bf16* __restrict__ yb) {
    __shared__ float red[4];
    int t = blockIdx.x, tid = threadIdx.x;
    const bf16* row = zx + (size_t)t * N1;
    float v[8];
    float ss = 0.f;
#pragma unroll
    for (int i = 0; i < 8; i++) {
        v[i] = __bfloat162float(row[tid + i * 256]);
        ss += v[i] * v[i];
    }
#pragma unroll
    for (int d = 32; d > 0; d >>= 1) ss += __shfl_down(ss, d);
    if ((tid & 63) == 0) red[tid >> 6] = ss;
    __syncthreads();
    float scale = rsqrtf((red[0] + red[1] + red[2] + red[3]) * (1.0f / DINNER) + 1e-5f);
#pragma unroll
    for (int i = 0; i < 8; i++) {
        int col = tid + i * 256;
        yb[(size_t)t * DINNER + col] = __float2bfloat16(v[i] * scale * nw[col]);
    }
}

extern "C" void kernel_launch(void* const* d_in, const int* in_sizes, int n_in,
                              void* d_out, int out_size, void* d_ws, size_t ws_size,
                              hipStream_t stream) {
    const float* u       = (const float*)d_in[0];
    const float* W_in    = (const float*)d_in[1];
    const float* conv_w  = (const float*)d_in[2];
    const float* conv_b  = (const float*)d_in[3];
    const float* dt_bias = (const float*)d_in[4];
    const float* A_log   = (const float*)d_in[5];
    const float* Dp      = (const float*)d_in[6];
    const float* norm_w  = (const float*)d_in[7];
    const float* W_out   = (const float*)d_in[8];
    float* out = (float*)d_out;

    // Workspace layout (~105 MiB total):
    char* ws = (char*)d_ws;
    bf16* zx     = (bf16*)ws;  ws += (size_t)MTOT * N1 * 2;       // 69.2 MB
    bf16* xbc    = (bf16*)ws;  ws += (size_t)MTOT * CONVD * 2;    // 34 MB (reused as y_b)
    bf16* wout_b = (bf16*)ws;  ws += (size_t)DMODEL * DINNER * 2; // 4 MB
    float* dtb   = (float*)ws; ws += (size_t)MTOT * NH * 4;       // 1 MB
    float* td    = (float*)ws; ws += (size_t)BSZ * NCH * NH * 4;  // 16 KB
    bf16* y_b    = (bf16*)xbc;  // xbc dead after k_y; y_b written by k_norm after

    // d_out (32 MiB) doubles as scratch: u_b/win_b live during GEMM1 only;
    // st (exactly 32 MiB bf16) lives from k_cstate until k_y; GEMM2 writes out last.
    bf16* u_b   = (bf16*)d_out;                                   // 16 MB
    bf16* win_b = (bf16*)((char*)d_out + (size_t)MTOT * DMODEL * 2); // 8.25 MB
    bf16* st    = (bf16*)d_out;                                   // 32 MB (after GEMM1)

    k_cvt<<<(MTOT * DMODEL + 255) / 256, 256, 0, stream>>>(u, u_b, MTOT * DMODEL);
    k_cvt<<<(N1 * DMODEL + 255) / 256, 256, 0, stream>>>(W_in, win_b, N1 * DMODEL);
    k_cvt<<<(DMODEL * DINNER + 255) / 256, 256, 0, stream>>>(W_out, wout_b, DMODEL * DINNER);

    k_dtproj<<<MTOT, 256, 0, stream>>>(u, W_in, dt_bias, dtb);

    k_gemm_bt<bf16><<<dim3(N1 / 128, MTOT / 128), 256, 0, stream>>>(u_b, win_b, zx, N1, DMODEL);

    k_conv<<<(MTOT * CONVD + 255) / 256, 256, 0, stream>>>(zx, conv_w, conv_b, xbc);

    k_cstate<<<dim3(NH, NCH, BSZ), 256, 0, stream>>>(xbc, dtb, A_log, st, td);
    k_scan<<<(BSZ * NH * HD * DSTATE + 255) / 256, 256, 0, stream>>>(st, td);
    k_y<<<dim3(NH, NCH, BSZ), 256, 0, stream>>>(xbc, dtb, A_log, Dp, st, zx);

    k_norm<<<MTOT, 256, 0, stream>>>(zx, norm_w, y_b);

    k_gemm_bt<float><<<dim3(DMODEL / 128, MTOT / 128), 256, 0, stream>>>(y_b, wout_b, out, DMODEL, DINNER);
}

// Round 3
// 524.126 us; speedup vs baseline: 4.0488x; 4.0488x over previous
//
#include <hip/hip_runtime.h>
#include <hip/hip_bf16.h>

#define BSZ 4
#define SEQ 2048
#define DMODEL 1024
#define DINNER 2048
#define DSTATE 64
#define NH 32
#define HD 64
#define CKL 64            // chunk length
#define NCH 32            // chunks per sequence
#define CONVD 2176
#define DPROJ 4256
#define N1 4224           // GEMM1 N = DINNER + CONVD = 33*128 (dt cols handled separately)
#define MTOT 8192         // BSZ*SEQ
#define LSTR 68           // LDS row stride (floats) for k_cstate
#define YSTR 72           // LDS row stride (bf16) for k_y tiles: 144 B, 16B-aligned rows

typedef __hip_bfloat16 bf16;
typedef __attribute__((ext_vector_type(8))) short short8;   // 8 bf16 (4 VGPRs)
typedef __attribute__((ext_vector_type(4))) short short4_;  // 8 bytes
typedef __attribute__((ext_vector_type(4))) float f32x4;

__device__ __forceinline__ float sigmoidf_(float x) { return 1.0f / (1.0f + __expf(-x)); }
__device__ __forceinline__ float bits2f(short s) { return __uint_as_float(((unsigned)(unsigned short)s) << 16); }
__device__ __forceinline__ short f2bits(float f) {
    bf16 h = __float2bfloat16(f);
    return *reinterpret_cast<short*>(&h);
}

__device__ __forceinline__ void gl_lds16(const bf16* g, bf16* l) {
    __builtin_amdgcn_global_load_lds((const __attribute__((address_space(1))) void*)g,
                                     (__attribute__((address_space(3))) void*)l, 16, 0, 0);
}

__device__ __forceinline__ void store_val(float* p, float v) { *p = v; }
__device__ __forceinline__ void store_val(bf16* p, float v) { *p = __float2bfloat16(v); }

// ---------------- fp32 -> bf16 convert ----------------
__global__ void k_cvt(const float* __restrict__ src, bf16* __restrict__ dst, int n) {
    int i = blockIdx.x * 256 + threadIdx.x;
    if (i < n) dst[i] = __float2bfloat16(src[i]);
}

// ---------------- bf16 MFMA GEMM: C[M][N] = A[M][K] * W[N][K]^T ----------------
template <typename TOUT>
__global__ __launch_bounds__(256) void k_gemm_bt(const bf16* __restrict__ A, const bf16* __restrict__ W,
                                                 TOUT* __restrict__ C, int N, int K) {
    __shared__ __align__(16) bf16 lA[128 * 32];
    __shared__ __align__(16) bf16 lB[128 * 32];
    const int tid = threadIdx.x;
    const int lane = tid & 63, w = tid >> 6;
    const int wm = w >> 1, wn = w & 1;
    const int lr = lane & 15, lk = lane >> 4;
    const int m0 = blockIdx.y * 128, n0 = blockIdx.x * 128;

    f32x4 acc[4][4];
#pragma unroll
    for (int i = 0; i < 4; i++)
#pragma unroll
        for (int j = 0; j < 4; j++) acc[i][j] = (f32x4){0.f, 0.f, 0.f, 0.f};

    const int r = tid >> 2;
    const int cs = (tid & 3) * 8;
    const bf16* ga = A + (size_t)(m0 + r) * K + cs;
    const bf16* gb = W + (size_t)(n0 + r) * K + cs;
    bf16* la0 = lA + tid * 8;
    bf16* lb0 = lB + tid * 8;

    for (int kt = 0; kt < K; kt += 32) {
        gl_lds16(ga + kt, la0);
        gl_lds16(ga + kt + (size_t)64 * K, la0 + 64 * 32);
        gl_lds16(gb + kt, lb0);
        gl_lds16(gb + kt + (size_t)64 * K, lb0 + 64 * 32);
        __syncthreads();
        short8 af[4], bfr[4];
#pragma unroll
        for (int im = 0; im < 4; im++)
            af[im] = *(const short8*)&lA[(wm * 64 + im * 16 + lr) * 32 + lk * 8];
#pragma unroll
        for (int jn = 0; jn < 4; jn++)
            bfr[jn] = *(const short8*)&lB[(wn * 64 + jn * 16 + lr) * 32 + lk * 8];
#pragma unroll
        for (int im = 0; im < 4; im++)
#pragma unroll
            for (int jn = 0; jn < 4; jn++)
                acc[im][jn] = __builtin_amdgcn_mfma_f32_16x16x32_bf16(af[im], bfr[jn], acc[im][jn], 0, 0, 0);
        __syncthreads();
    }
#pragma unroll
    for (int im = 0; im < 4; im++) {
        int row = m0 + wm * 64 + im * 16 + lk * 4;
#pragma unroll
        for (int jn = 0; jn < 4; jn++) {
            int col = n0 + wn * 64 + jn * 16 + lr;
            TOUT* cp = C + (size_t)row * N + col;
#pragma unroll
            for (int rr = 0; rr < 4; rr++) store_val(cp + (size_t)rr * N, acc[im][jn][rr]);
        }
    }
}

// ---------------- dt projection (fp32) ----------------
__global__ __launch_bounds__(256) void k_dtproj(const float* __restrict__ u, const float* __restrict__ W_in,
                                                const float* __restrict__ dt_bias, float* __restrict__ dtb) {
    const int t = blockIdx.x;
    const int h = threadIdx.x >> 3, sub = threadIdx.x & 7;
    const float* ur = u + (size_t)t * DMODEL;
    const float* wr = W_in + (size_t)(DPROJ - NH + h) * DMODEL;
    float s = 0.f;
    for (int k = sub * 4; k < DMODEL; k += 32)
        s += ur[k] * wr[k] + ur[k + 1] * wr[k + 1] + ur[k + 2] * wr[k + 2] + ur[k + 3] * wr[k + 3];
    s += __shfl_down(s, 4, 8);
    s += __shfl_down(s, 2, 8);
    s += __shfl_down(s, 1, 8);
    if (sub == 0) {
        float x = s + dt_bias[h];
        dtb[(size_t)t * NH + h] = (x > 20.f) ? x : log1pf(__expf(x));
    }
}

// ---------------- depthwise causal conv (width 4) + bias + SiLU ----------------
__global__ void k_conv(const bf16* __restrict__ zx, const float* __restrict__ cw,
                       const float* __restrict__ cb, bf16* __restrict__ xbc) {
    int i = blockIdx.x * 256 + threadIdx.x;
    if (i >= MTOT * CONVD) return;
    int c = i % CONVD;
    int t = i / CONVD;
    int s = t & (SEQ - 1);
    float acc = cb[c];
    const bf16* base = zx + (size_t)t * N1 + DINNER + c;
#pragma unroll
    for (int k = 0; k < 4; k++) {
        int st = s - 3 + k;
        if (st >= 0) acc += __bfloat162float(base[(long)(k - 3) * N1]) * cw[c * 4 + k];
    }
    xbc[i] = __float2bfloat16(acc * sigmoidf_(acc));
}

// ---------------- per-(b,c,h): chunk state S[p][n] = sum_l exp(tot-Ac[l])*dt[l]*B[l][n]*x[l][p] --------
__global__ __launch_bounds__(256) void k_cstate(const bf16* __restrict__ xbc, const float* __restrict__ dt,
                                                const float* __restrict__ A_log, bf16* __restrict__ states,
                                                float* __restrict__ totdec) {
    __shared__ __align__(16) float Bs[CKL * LSTR];
    __shared__ __align__(16) float Xs[CKL * LSTR];
    __shared__ float sdt[CKL], sAc[CKL];
    const int h = blockIdx.x, c = blockIdx.y, b = blockIdx.z;
    const int tid = threadIdx.x;
    const int row0 = b * SEQ + c * CKL;
    const float Ah = -__expf(A_log[h]);

    if (tid < 64) {
        float dv = dt[(size_t)(row0 + tid) * NH + h];
        sdt[tid] = dv;
        float v = Ah * dv;
#pragma unroll
        for (int d = 1; d < 64; d <<= 1) {
            float o = __shfl_up(v, d);
            if (tid >= d) v += o;
        }
        sAc[tid] = v;
    }
#pragma unroll
    for (int it = 0; it < 16; it++) {
        int idx = it * 256 + tid;
        int l = idx >> 6, n = idx & 63;
        const bf16* rp = xbc + (size_t)(row0 + l) * CONVD;
        Bs[l * LSTR + n] = __bfloat162float(rp[DINNER + n]);
        Xs[l * LSTR + n] = __bfloat162float(rp[h * HD + n]);
    }
    __syncthreads();
    const float tot = sAc[63];
    if (tid == 0) totdec[(b * NCH + c) * NH + h] = tot;
#pragma unroll
    for (int it = 0; it < 16; it++) {
        int idx = it * 256 + tid;
        int l = idx >> 6, n = idx & 63;
        Bs[l * LSTR + n] *= __expf(tot - sAc[l]) * sdt[l];
    }
    __syncthreads();
    const int p0 = (tid >> 4) * 4, n0 = (tid & 15) * 4;
    float acc[4][4] = {};
    for (int l = 0; l < CKL; l++) {
        f32x4 xv = *(const f32x4*)&Xs[l * LSTR + p0];
        f32x4 bv = *(const f32x4*)&Bs[l * LSTR + n0];
#pragma unroll
        for (int i = 0; i < 4; i++)
#pragma unroll
            for (int j = 0; j < 4; j++) acc[i][j] += xv[i] * bv[j];
    }
    bf16* sp = states + (((size_t)(b * NCH + c) * NH + h) << 12);
#pragma unroll
    for (int i = 0; i < 4; i++)
#pragma unroll
        for (int j = 0; j < 4; j++) sp[(p0 + i) * 64 + n0 + j] = __float2bfloat16(acc[i][j]);
}

// ---------------- inter-chunk scan ----------------
__global__ void k_scan(bf16* __restrict__ states, const float* __restrict__ totdec) {
    int i = blockIdx.x * 256 + threadIdx.x;
    if (i >= BSZ * NH * HD * DSTATE) return;
    int pn = i & 4095;
    int h = (i >> 12) & 31;
    int b = i >> 17;
    float s = 0.f;
    size_t strideC = (size_t)NH << 12;
    size_t off = (((size_t)(b * NCH) * NH + h) << 12) + pn;
    for (int c = 0; c < NCH; c++) {
        float v = __bfloat162float(states[off]);
        states[off] = __float2bfloat16(s);
        s = s * __expf(totdec[(b * NCH + c) * NH + h]) + v;
        off += strideC;
    }
}

// ---------------- per-(b,c,h): Y = Y_diag + Y_off + D*x, gate with silu(z) — MFMA version ----------
// Per block: three 64x64x64 bf16 matmuls on matrix cores.
//   P1: acc[l][p] = sum_n C[l][n] * S0[p][n]           (A=C rows, B=S0 rows)
//   scale acc by exp(Ac[l])
//   P2: G[l][s]  = sum_n C[l][n] * B[s][n], then mask/decay, round-trip LDS (C/D -> A layout)
//   P3: acc[l][p] += sum_s G[l][s] * Xt[p][s]          (A=G rows, B=Xt rows)
// Wave w owns output rows l in [16w,16w+16).
__global__ __launch_bounds__(256) void k_y(const bf16* __restrict__ xbc, const float* __restrict__ dt,
                                           const float* __restrict__ A_log, const float* __restrict__ Dp,
                                           const bf16* __restrict__ states, bf16* __restrict__ zx) {
    __shared__ __align__(16) short Cs[CKL * YSTR];
    __shared__ __align__(16) short Bs[CKL * YSTR];
    __shared__ __align__(16) short Ss[CKL * YSTR];   // S0[p][n]
    __shared__ __align__(16) short Xt[CKL * YSTR];   // X transposed: [p][s]
    __shared__ __align__(16) short Gs[4 * 16 * YSTR];// per-wave G tiles [l_local][s]
    __shared__ float sdt[CKL], sAc[CKL];
    const int h = blockIdx.x, c = blockIdx.y, b = blockIdx.z;
    const int tid = threadIdx.x;
    const int row0 = b * SEQ + c * CKL;
    const float Ah = -__expf(A_log[h]);
    const float Dh = Dp[h];

    if (tid < 64) {  // wave 0: dt + inclusive scan of A*dt
        float dv = dt[(size_t)(row0 + tid) * NH + h];
        sdt[tid] = dv;
        float v = Ah * dv;
#pragma unroll
        for (int d = 1; d < 64; d <<= 1) {
            float o = __shfl_up(v, d);
            if (tid >= d) v += o;
        }
        sAc[tid] = v;
    }
    // cooperative tile loads: 4 iters x 4 consecutive bf16 per thread (8B vector loads)
    const short* spg = (const short*)(states + (((size_t)(b * NCH + c) * NH + h) << 12));
    {
        const int n0 = (tid & 15) * 4;
#pragma unroll
        for (int it = 0; it < 4; it++) {
            int l = it * 16 + (tid >> 4);
            const short* rp = (const short*)(xbc + (size_t)(row0 + l) * CONVD);
            *(short4_*)&Cs[l * YSTR + n0] = *(const short4_*)&rp[DINNER + DSTATE + n0];
            *(short4_*)&Bs[l * YSTR + n0] = *(const short4_*)&rp[DINNER + n0];
            *(short4_*)&Ss[l * YSTR + n0] = *(const short4_*)&spg[l * 64 + n0];
            short4_ x4 = *(const short4_*)&rp[h * HD + n0];
#pragma unroll
            for (int j = 0; j < 4; j++) Xt[(n0 + j) * YSTR + l] = x4[j];
        }
    }
    __syncthreads();

    const int lane = tid & 63, w = tid >> 6;
    const int lr = lane & 15, lk = lane >> 4;
    short* gw = Gs + w * 16 * YSTR;

    // A-frags of C (shared by P1 and P2): rows 16w+lr
    short8 cf0 = *(const short8*)&Cs[(16 * w + lr) * YSTR + lk * 8];
    short8 cf1 = *(const short8*)&Cs[(16 * w + lr) * YSTR + 32 + lk * 8];

    // P1: Y_off
    f32x4 acc[4];
#pragma unroll
    for (int t = 0; t < 4; t++) {
        short8 s0 = *(const short8*)&Ss[(16 * t + lr) * YSTR + lk * 8];
        short8 s1 = *(const short8*)&Ss[(16 * t + lr) * YSTR + 32 + lk * 8];
        acc[t] = __builtin_amdgcn_mfma_f32_16x16x32_bf16(cf0, s0, (f32x4){0.f, 0.f, 0.f, 0.f}, 0, 0, 0);
        acc[t] = __builtin_amdgcn_mfma_f32_16x16x32_bf16(cf1, s1, acc[t], 0, 0, 0);
    }
    float sAcl[4], el[4];
#pragma unroll
    for (int r = 0; r < 4; r++) {
        sAcl[r] = sAc[16 * w + lk * 4 + r];
        el[r] = __expf(sAcl[r]);
    }
#pragma unroll
    for (int t = 0; t < 4; t++)
#pragma unroll
        for (int r = 0; r < 4; r++) acc[t][r] *= el[r];

    // P2: G = C * B^T, mask/decay, write to wave-private LDS as bf16
#pragma unroll
    for (int t = 0; t < 4; t++) {
        short8 b0 = *(const short8*)&Bs[(16 * t + lr) * YSTR + lk * 8];
        short8 b1 = *(const short8*)&Bs[(16 * t + lr) * YSTR + 32 + lk * 8];
        f32x4 g = __builtin_amdgcn_mfma_f32_16x16x32_bf16(cf0, b0, (f32x4){0.f, 0.f, 0.f, 0.f}, 0, 0, 0);
        g = __builtin_amdgcn_mfma_f32_16x16x32_bf16(cf1, b1, g, 0, 0, 0);
        int s = 16 * t + lr;
        float sAcs = sAc[s], dts = sdt[s];
#pragma unroll
        for (int r = 0; r < 4; r++) {
            int l = 16 * w + lk * 4 + r;
            float v = (s <= l) ? g[r] * __expf(sAcl[r] - sAcs) * dts : 0.f;
            gw[(lk * 4 + r) * YSTR + s] = f2bits(v);
        }
    }
    // P3: acc += G * X   (A-frags from Gs, B-frags from Xt; within-wave LDS RAW, no barrier)
    short8 gf0 = *(const short8*)&gw[lr * YSTR + lk * 8];
    short8 gf1 = *(const short8*)&gw[lr * YSTR + 32 + lk * 8];
#pragma unroll
    for (int t = 0; t < 4; t++) {
        short8 x0 = *(const short8*)&Xt[(16 * t + lr) * YSTR + lk * 8];
        short8 x1 = *(const short8*)&Xt[(16 * t + lr) * YSTR + 32 + lk * 8];
        acc[t] = __builtin_amdgcn_mfma_f32_16x16x32_bf16(gf0, x0, acc[t], 0, 0, 0);
        acc[t] = __builtin_amdgcn_mfma_f32_16x16x32_bf16(gf1, x1, acc[t], 0, 0, 0);
    }
    // D*x, gate with silu(z), write in-place into zx cols [h*64, h*64+64)
#pragma unroll
    for (int t = 0; t < 4; t++) {
        int p = 16 * t + lr;
#pragma unroll
        for (int r = 0; r < 4; r++) {
            int l = 16 * w + lk * 4 + r;
            float y = acc[t][r] + Dh * bits2f(Xt[p * YSTR + l]);
            size_t zi = (size_t)(row0 + l) * N1 + h * HD + p;
            float z = __bfloat162float(zx[zi]);
            zx[zi] = __float2bfloat16(y * (z * sigmoidf_(z)));
        }
    }
}

// ---------------- RMSNorm over DINNER + bf16 cast for GEMM2 ----------------
__global__ __launch_bounds__(256) void k_norm(const bf16* __restrict__ zx, const float* __restrict__ nw,
                                              bf16* __restrict__ yb) {
    __shared__ float red[4];
    int t = blockIdx.x, tid = threadIdx.x;
    const bf16* row = zx + (size_t)t * N1;
    float v[8];
    float ss = 0.f;
#pragma unroll
    for (int i = 0; i < 8; i++) {
        v[i] = __bfloat162float(row[tid + i * 256]);
        ss += v[i] * v[i];
    }
#pragma unroll
    for (int d = 32; d > 0; d >>= 1) ss += __shfl_down(ss, d);
    if ((tid & 63) == 0) red[tid >> 6] = ss;
    __syncthreads();
    float scale = rsqrtf((red[0] + red[1] + red[2] + red[3]) * (1.0f / DINNER) + 1e-5f);
#pragma unroll
    for (int i = 0; i < 8; i++) {
        int col = tid + i * 256;
        yb[(size_t)t * DINNER + col] = __float2bfloat16(v[i] * scale * nw[col]);
    }
}

extern "C" void kernel_launch(void* const* d_in, const int* in_sizes, int n_in,
                              void* d_out, int out_size, void* d_ws, size_t ws_size,
                              hipStream_t stream) {
    const float* u       = (const float*)d_in[0];
    const float* W_in    = (const float*)d_in[1];
    const float* conv_w  = (const float*)d_in[2];
    const float* conv_b  = (const float*)d_in[3];
    const float* dt_bias = (const float*)d_in[4];
    const float* A_log   = (const float*)d_in[5];
    const float* Dp      = (const float*)d_in[6];
    const float* norm_w  = (const float*)d_in[7];
    const float* W_out   = (const float*)d_in[8];
    float* out = (float*)d_out;

    // Workspace layout (~105 MiB total):
    char* ws = (char*)d_ws;
    bf16* zx     = (bf16*)ws;  ws += (size_t)MTOT * N1 * 2;       // 69.2 MB
    bf16* xbc    = (bf16*)ws;  ws += (size_t)MTOT * CONVD * 2;    // 34 MB (reused as y_b)
    bf16* wout_b = (bf16*)ws;  ws += (size_t)DMODEL * DINNER * 2; // 4 MB
    float* dtb   = (float*)ws; ws += (size_t)MTOT * NH * 4;       // 1 MB
    float* td    = (float*)ws; ws += (size_t)BSZ * NCH * NH * 4;  // 16 KB
    bf16* y_b    = (bf16*)xbc;  // xbc dead after k_y; y_b written by k_norm after

    // d_out (32 MiB) doubles as scratch: u_b/win_b live during GEMM1 only;
    // st (exactly 32 MiB bf16) lives from k_cstate until k_y; GEMM2 writes out last.
    bf16* u_b   = (bf16*)d_out;                                   // 16 MB
    bf16* win_b = (bf16*)((char*)d_out + (size_t)MTOT * DMODEL * 2); // 8.25 MB
    bf16* st    = (bf16*)d_out;                                   // 32 MB (after GEMM1)

    k_cvt<<<(MTOT * DMODEL + 255) / 256, 256, 0, stream>>>(u, u_b, MTOT * DMODEL);
    k_cvt<<<(N1 * DMODEL + 255) / 256, 256, 0, stream>>>(W_in, win_b, N1 * DMODEL);
    k_cvt<<<(DMODEL * DINNER + 255) / 256, 256, 0, stream>>>(W_out, wout_b, DMODEL * DINNER);

    k_dtproj<<<MTOT, 256, 0, stream>>>(u, W_in, dt_bias, dtb);

    k_gemm_bt<bf16><<<dim3(N1 / 128, MTOT / 128), 256, 0, stream>>>(u_b, win_b, zx, N1, DMODEL);

    k_conv<<<(MTOT * CONVD + 255) / 256, 256, 0, stream>>>(zx, conv_w, conv_b, xbc);

    k_cstate<<<dim3(NH, NCH, BSZ), 256, 0, stream>>>(xbc, dtb, A_log, st, td);
    k_scan<<<(BSZ * NH * HD * DSTATE + 255) / 256, 256, 0, stream>>>(st, td);
    k_y<<<dim3(NH, NCH, BSZ), 256, 0, stream>>>(xbc, dtb, A_log, Dp, st, zx);

    k_norm<<<MTOT, 256, 0, stream>>>(zx, norm_w, y_b);

    k_gemm_bt<float><<<dim3(DMODEL / 128, MTOT / 128), 256, 0, stream>>>(y_b, wout_b, out, DMODEL, DINNER);
}

// Round 4
// 457.848 us; speedup vs baseline: 4.6349x; 1.1448x over previous
//
#include <hip/hip_runtime.h>
#include <hip/hip_bf16.h>

#define BSZ 4
#define SEQ 2048
#define DMODEL 1024
#define DINNER 2048
#define DSTATE 64
#define NH 32
#define HD 64
#define CKL 64            // chunk length
#define NCH 32            // chunks per sequence
#define CONVD 2176
#define DPROJ 4256
#define N1 4224           // GEMM1 N = DINNER + CONVD = 33*128 (dt cols handled separately)
#define MTOT 8192         // BSZ*SEQ
#define YSTR 72           // LDS row stride (bf16): 144 B, keeps 16B alignment, ~2-way banks on b128

typedef __hip_bfloat16 bf16;
typedef __attribute__((ext_vector_type(8))) short short8;   // 8 bf16 (4 VGPRs)
typedef __attribute__((ext_vector_type(4))) short short4_;  // 8 bytes
typedef __attribute__((ext_vector_type(4))) float f32x4;

__device__ __forceinline__ float sigmoidf_(float x) { return 1.0f / (1.0f + __expf(-x)); }
__device__ __forceinline__ float bits2f(short s) { return __uint_as_float(((unsigned)(unsigned short)s) << 16); }
__device__ __forceinline__ short f2bits(float f) {
    bf16 h = __float2bfloat16(f);
    return *reinterpret_cast<short*>(&h);
}

__device__ __forceinline__ void gl_lds16(const bf16* g, bf16* l) {
    __builtin_amdgcn_global_load_lds((const __attribute__((address_space(1))) void*)g,
                                     (__attribute__((address_space(3))) void*)l, 16, 0, 0);
}

__device__ __forceinline__ void store_val(float* p, float v) { *p = v; }
__device__ __forceinline__ void store_val(bf16* p, float v) { *p = __float2bfloat16(v); }

// ---------------- fp32 -> bf16 convert (vectorized: 4 elems/thread; n % 4 == 0) ----------------
__global__ void k_cvt(const float* __restrict__ src, bf16* __restrict__ dst, int n) {
    int i = blockIdx.x * 256 + threadIdx.x;
    int g = i * 4;
    if (g < n) {
        f32x4 f = *(const f32x4*)&src[g];
        short4_ o;
#pragma unroll
        for (int j = 0; j < 4; j++) o[j] = f2bits(f[j]);
        *(short4_*)&dst[g] = o;
    }
}

// ---------------- bf16 MFMA GEMM: C[M][N] = A[M][K] * W[N][K]^T ----------------
template <typename TOUT>
__global__ __launch_bounds__(256) void k_gemm_bt(const bf16* __restrict__ A, const bf16* __restrict__ W,
                                                 TOUT* __restrict__ C, int N, int K) {
    __shared__ __align__(16) bf16 lA[128 * 32];
    __shared__ __align__(16) bf16 lB[128 * 32];
    const int tid = threadIdx.x;
    const int lane = tid & 63, w = tid >> 6;
    const int wm = w >> 1, wn = w & 1;
    const int lr = lane & 15, lk = lane >> 4;
    const int m0 = blockIdx.y * 128, n0 = blockIdx.x * 128;

    f32x4 acc[4][4];
#pragma unroll
    for (int i = 0; i < 4; i++)
#pragma unroll
        for (int j = 0; j < 4; j++) acc[i][j] = (f32x4){0.f, 0.f, 0.f, 0.f};

    const int r = tid >> 2;
    const int cs = (tid & 3) * 8;
    const bf16* ga = A + (size_t)(m0 + r) * K + cs;
    const bf16* gb = W + (size_t)(n0 + r) * K + cs;
    bf16* la0 = lA + tid * 8;
    bf16* lb0 = lB + tid * 8;

    for (int kt = 0; kt < K; kt += 32) {
        gl_lds16(ga + kt, la0);
        gl_lds16(ga + kt + (size_t)64 * K, la0 + 64 * 32);
        gl_lds16(gb + kt, lb0);
        gl_lds16(gb + kt + (size_t)64 * K, lb0 + 64 * 32);
        __syncthreads();
        short8 af[4], bfr[4];
#pragma unroll
        for (int im = 0; im < 4; im++)
            af[im] = *(const short8*)&lA[(wm * 64 + im * 16 + lr) * 32 + lk * 8];
#pragma unroll
        for (int jn = 0; jn < 4; jn++)
            bfr[jn] = *(const short8*)&lB[(wn * 64 + jn * 16 + lr) * 32 + lk * 8];
#pragma unroll
        for (int im = 0; im < 4; im++)
#pragma unroll
            for (int jn = 0; jn < 4; jn++)
                acc[im][jn] = __builtin_amdgcn_mfma_f32_16x16x32_bf16(af[im], bfr[jn], acc[im][jn], 0, 0, 0);
        __syncthreads();
    }
#pragma unroll
    for (int im = 0; im < 4; im++) {
        int row = m0 + wm * 64 + im * 16 + lk * 4;
#pragma unroll
        for (int jn = 0; jn < 4; jn++) {
            int col = n0 + wn * 64 + jn * 16 + lr;
            TOUT* cp = C + (size_t)row * N + col;
#pragma unroll
            for (int rr = 0; rr < 4; rr++) store_val(cp + (size_t)rr * N, acc[im][jn][rr]);
        }
    }
}

// ---------------- dt projection (fp32) ----------------
__global__ __launch_bounds__(256) void k_dtproj(const float* __restrict__ u, const float* __restrict__ W_in,
                                                const float* __restrict__ dt_bias, float* __restrict__ dtb) {
    const int t = blockIdx.x;
    const int h = threadIdx.x >> 3, sub = threadIdx.x & 7;
    const float* ur = u + (size_t)t * DMODEL;
    const float* wr = W_in + (size_t)(DPROJ - NH + h) * DMODEL;
    float s = 0.f;
    for (int k = sub * 4; k < DMODEL; k += 32)
        s += ur[k] * wr[k] + ur[k + 1] * wr[k + 1] + ur[k + 2] * wr[k + 2] + ur[k + 3] * wr[k + 3];
    s += __shfl_down(s, 4, 8);
    s += __shfl_down(s, 2, 8);
    s += __shfl_down(s, 1, 8);
    if (sub == 0) {
        float x = s + dt_bias[h];
        dtb[(size_t)t * NH + h] = (x > 20.f) ? x : log1pf(__expf(x));
    }
}

// ---------------- depthwise causal conv (width 4) + bias + SiLU — 4 channels/thread ----------------
__global__ void k_conv(const bf16* __restrict__ zx, const float* __restrict__ cw,
                       const float* __restrict__ cb, bf16* __restrict__ xbc) {
    int i = blockIdx.x * 256 + threadIdx.x;
    int g = i * 4;
    if (g >= MTOT * CONVD) return;
    int c0 = g % CONVD;
    int t = g / CONVD;
    int s = t & (SEQ - 1);
    const short* base = (const short*)(zx + (size_t)t * N1 + DINNER + c0);
    f32x4 w0 = *(const f32x4*)&cw[(c0 + 0) * 4];
    f32x4 w1 = *(const f32x4*)&cw[(c0 + 1) * 4];
    f32x4 w2 = *(const f32x4*)&cw[(c0 + 2) * 4];
    f32x4 w3 = *(const f32x4*)&cw[(c0 + 3) * 4];
    f32x4 a = *(const f32x4*)&cb[c0];
#pragma unroll
    for (int k = 0; k < 4; k++) {
        int st = s - 3 + k;
        if (st >= 0) {
            short4_ v = *(const short4_*)(base + (long)(k - 3) * N1);
            a[0] += bits2f(v[0]) * w0[k];
            a[1] += bits2f(v[1]) * w1[k];
            a[2] += bits2f(v[2]) * w2[k];
            a[3] += bits2f(v[3]) * w3[k];
        }
    }
    short4_ o;
#pragma unroll
    for (int j = 0; j < 4; j++) o[j] = f2bits(a[j] * sigmoidf_(a[j]));
    *(short4_*)&xbc[g] = o;
}

// ---------------- per-(b,c,h): chunk state S[p][n] = sum_l exp(tot-Ac[l])*dt[l]*B[l][n]*x[l][p] ------
// MFMA: S = Xt (A-op, rows p, k=l contiguous) x Btd (B-op, rows n, k=l contiguous), K=64.
__global__ __launch_bounds__(256) void k_cstate(const bf16* __restrict__ xbc, const float* __restrict__ dt,
                                                const float* __restrict__ A_log, bf16* __restrict__ states,
                                                float* __restrict__ totdec) {
    __shared__ __align__(16) short Bt[CKL * YSTR];   // [n][l]
    __shared__ __align__(16) short Xt[CKL * YSTR];   // [p][l]
    __shared__ float sf[CKL];                        // exp(tot - Ac[l]) * dt[l]
    const int h = blockIdx.x, c = blockIdx.y, b = blockIdx.z;
    const int tid = threadIdx.x;
    const int row0 = b * SEQ + c * CKL;
    const float Ah = -__expf(A_log[h]);

    if (tid < 64) {  // wave 0: dt load + inclusive scan of A*dt
        float dv = dt[(size_t)(row0 + tid) * NH + h];
        float v = Ah * dv;
#pragma unroll
        for (int d = 1; d < 64; d <<= 1) {
            float o = __shfl_up(v, d);
            if (tid >= d) v += o;
        }
        float tot = __shfl(v, 63);
        sf[tid] = __expf(tot - v) * dv;
        if (tid == 63) totdec[(b * NCH + c) * NH + h] = tot;
    }
    // cooperative loads with transpose scatter (raw B; decay applied after barrier)
    {
        const int n0 = (tid & 15) * 4;
#pragma unroll
        for (int it = 0; it < 4; it++) {
            int l = it * 16 + (tid >> 4);
            const short* rp = (const short*)(xbc + (size_t)(row0 + l) * CONVD);
            short4_ b4 = *(const short4_*)&rp[DINNER + n0];
            short4_ x4 = *(const short4_*)&rp[h * HD + n0];
#pragma unroll
            for (int j = 0; j < 4; j++) {
                Bt[(n0 + j) * YSTR + l] = b4[j];
                Xt[(n0 + j) * YSTR + l] = x4[j];
            }
        }
    }
    __syncthreads();
    // scale Bt[n][l] by sf[l] in place
    {
        const int l0 = (tid & 15) * 4;
        f32x4 f = *(const f32x4*)&sf[l0];
#pragma unroll
        for (int it = 0; it < 4; it++) {
            int n = it * 16 + (tid >> 4);
            short* p = &Bt[n * YSTR + l0];
            short4_ v = *(short4_*)p;
#pragma unroll
            for (int j = 0; j < 4; j++) v[j] = f2bits(bits2f(v[j]) * f[j]);
            *(short4_*)p = v;
        }
    }
    __syncthreads();
    const int lane = tid & 63, w = tid >> 6;
    const int lr = lane & 15, lk = lane >> 4;
    short8 af0 = *(const short8*)&Xt[(16 * w + lr) * YSTR + lk * 8];
    short8 af1 = *(const short8*)&Xt[(16 * w + lr) * YSTR + 32 + lk * 8];
    f32x4 acc[4];
#pragma unroll
    for (int t = 0; t < 4; t++) {
        short8 b0 = *(const short8*)&Bt[(16 * t + lr) * YSTR + lk * 8];
        short8 b1 = *(const short8*)&Bt[(16 * t + lr) * YSTR + 32 + lk * 8];
        acc[t] = __builtin_amdgcn_mfma_f32_16x16x32_bf16(af0, b0, (f32x4){0.f, 0.f, 0.f, 0.f}, 0, 0, 0);
        acc[t] = __builtin_amdgcn_mfma_f32_16x16x32_bf16(af1, b1, acc[t], 0, 0, 0);
    }
    bf16* sp = states + (((size_t)(b * NCH + c) * NH + h) << 12);
#pragma unroll
    for (int t = 0; t < 4; t++) {
        int n = 16 * t + lr;
#pragma unroll
        for (int r = 0; r < 4; r++) {
            int p = 16 * w + lk * 4 + r;
            sp[p * 64 + n] = __float2bfloat16(acc[t][r]);
        }
    }
}

// ---------------- inter-chunk scan ----------------
__global__ void k_scan(bf16* __restrict__ states, const float* __restrict__ totdec) {
    int i = blockIdx.x * 256 + threadIdx.x;
    if (i >= BSZ * NH * HD * DSTATE) return;
    int pn = i & 4095;
    int h = (i >> 12) & 31;
    int b = i >> 17;
    float s = 0.f;
    size_t strideC = (size_t)NH << 12;
    size_t off = (((size_t)(b * NCH) * NH + h) << 12) + pn;
    for (int c = 0; c < NCH; c++) {
        float v = __bfloat162float(states[off]);
        states[off] = __float2bfloat16(s);
        s = s * __expf(totdec[(b * NCH + c) * NH + h]) + v;
        off += strideC;
    }
}

// ---------------- per-(b,c,h): Y = Y_diag + Y_off + D*x, gate with silu(z) — MFMA ----------
__global__ __launch_bounds__(256) void k_y(const bf16* __restrict__ xbc, const float* __restrict__ dt,
                                           const float* __restrict__ A_log, const float* __restrict__ Dp,
                                           const bf16* __restrict__ states, bf16* __restrict__ zx) {
    __shared__ __align__(16) short Cs[CKL * YSTR];
    __shared__ __align__(16) short Bs[CKL * YSTR];
    __shared__ __align__(16) short Ss[CKL * YSTR];   // S0[p][n]
    __shared__ __align__(16) short Xt[CKL * YSTR];   // X transposed: [p][s]
    __shared__ __align__(16) short Gs[4 * 16 * YSTR];// per-wave G tiles [l_local][s]
    __shared__ float sdt[CKL], sAc[CKL];
    const int h = blockIdx.x, c = blockIdx.y, b = blockIdx.z;
    const int tid = threadIdx.x;
    const int row0 = b * SEQ + c * CKL;
    const float Ah = -__expf(A_log[h]);
    const float Dh = Dp[h];

    if (tid < 64) {
        float dv = dt[(size_t)(row0 + tid) * NH + h];
        sdt[tid] = dv;
        float v = Ah * dv;
#pragma unroll
        for (int d = 1; d < 64; d <<= 1) {
            float o = __shfl_up(v, d);
            if (tid >= d) v += o;
        }
        sAc[tid] = v;
    }
    const short* spg = (const short*)(states + (((size_t)(b * NCH + c) * NH + h) << 12));
    {
        const int n0 = (tid & 15) * 4;
#pragma unroll
        for (int it = 0; it < 4; it++) {
            int l = it * 16 + (tid >> 4);
            const short* rp = (const short*)(xbc + (size_t)(row0 + l) * CONVD);
            *(short4_*)&Cs[l * YSTR + n0] = *(const short4_*)&rp[DINNER + DSTATE + n0];
            *(short4_*)&Bs[l * YSTR + n0] = *(const short4_*)&rp[DINNER + n0];
            *(short4_*)&Ss[l * YSTR + n0] = *(const short4_*)&spg[l * 64 + n0];
            short4_ x4 = *(const short4_*)&rp[h * HD + n0];
#pragma unroll
            for (int j = 0; j < 4; j++) Xt[(n0 + j) * YSTR + l] = x4[j];
        }
    }
    __syncthreads();

    const int lane = tid & 63, w = tid >> 6;
    const int lr = lane & 15, lk = lane >> 4;
    short* gw = Gs + w * 16 * YSTR;

    short8 cf0 = *(const short8*)&Cs[(16 * w + lr) * YSTR + lk * 8];
    short8 cf1 = *(const short8*)&Cs[(16 * w + lr) * YSTR + 32 + lk * 8];

    // P1: Y_off = C * S0^T
    f32x4 acc[4];
#pragma unroll
    for (int t = 0; t < 4; t++) {
        short8 s0 = *(const short8*)&Ss[(16 * t + lr) * YSTR + lk * 8];
        short8 s1 = *(const short8*)&Ss[(16 * t + lr) * YSTR + 32 + lk * 8];
        acc[t] = __builtin_amdgcn_mfma_f32_16x16x32_bf16(cf0, s0, (f32x4){0.f, 0.f, 0.f, 0.f}, 0, 0, 0);
        acc[t] = __builtin_amdgcn_mfma_f32_16x16x32_bf16(cf1, s1, acc[t], 0, 0, 0);
    }
    float sAcl[4], el[4];
#pragma unroll
    for (int r = 0; r < 4; r++) {
        sAcl[r] = sAc[16 * w + lk * 4 + r];
        el[r] = __expf(sAcl[r]);
    }
#pragma unroll
    for (int t = 0; t < 4; t++)
#pragma unroll
        for (int r = 0; r < 4; r++) acc[t][r] *= el[r];

    // P2: G = C * B^T, mask/decay, round-trip wave-private LDS (C/D -> A layout)
#pragma unroll
    for (int t = 0; t < 4; t++) {
        short8 b0 = *(const short8*)&Bs[(16 * t + lr) * YSTR + lk * 8];
        short8 b1 = *(const short8*)&Bs[(16 * t + lr) * YSTR + 32 + lk * 8];
        f32x4 g = __builtin_amdgcn_mfma_f32_16x16x32_bf16(cf0, b0, (f32x4){0.f, 0.f, 0.f, 0.f}, 0, 0, 0);
        g = __builtin_amdgcn_mfma_f32_16x16x32_bf16(cf1, b1, g, 0, 0, 0);
        int s = 16 * t + lr;
        float sAcs = sAc[s], dts = sdt[s];
#pragma unroll
        for (int r = 0; r < 4; r++) {
            int l = 16 * w + lk * 4 + r;
            float v = (s <= l) ? g[r] * __expf(sAcl[r] - sAcs) * dts : 0.f;
            gw[(lk * 4 + r) * YSTR + s] = f2bits(v);
        }
    }
    // P3: acc += G * X
    short8 gf0 = *(const short8*)&gw[lr * YSTR + lk * 8];
    short8 gf1 = *(const short8*)&gw[lr * YSTR + 32 + lk * 8];
#pragma unroll
    for (int t = 0; t < 4; t++) {
        short8 x0 = *(const short8*)&Xt[(16 * t + lr) * YSTR + lk * 8];
        short8 x1 = *(const short8*)&Xt[(16 * t + lr) * YSTR + 32 + lk * 8];
        acc[t] = __builtin_amdgcn_mfma_f32_16x16x32_bf16(gf0, x0, acc[t], 0, 0, 0);
        acc[t] = __builtin_amdgcn_mfma_f32_16x16x32_bf16(gf1, x1, acc[t], 0, 0, 0);
    }
    // D*x, gate with silu(z), write in-place into zx cols [h*64, h*64+64)
#pragma unroll
    for (int t = 0; t < 4; t++) {
        int p = 16 * t + lr;
#pragma unroll
        for (int r = 0; r < 4; r++) {
            int l = 16 * w + lk * 4 + r;
            float y = acc[t][r] + Dh * bits2f(Xt[p * YSTR + l]);
            size_t zi = (size_t)(row0 + l) * N1 + h * HD + p;
            float z = __bfloat162float(zx[zi]);
            zx[zi] = __float2bfloat16(y * (z * sigmoidf_(z)));
        }
    }
}

// ---------------- RMSNorm over DINNER + bf16 cast for GEMM2 (contiguous 16B/lane) ----------------
__global__ __launch_bounds__(256) void k_norm(const bf16* __restrict__ zx, const float* __restrict__ nw,
                                              bf16* __restrict__ yb) {
    __shared__ float red[4];
    int t = blockIdx.x, tid = threadIdx.x;
    const short* row = (const short*)(zx + (size_t)t * N1);
    short8 v8 = *(const short8*)&row[tid * 8];
    float v[8];
    float ss = 0.f;
#pragma unroll
    for (int i = 0; i < 8; i++) {
        v[i] = bits2f(v8[i]);
        ss += v[i] * v[i];
    }
#pragma unroll
    for (int d = 32; d > 0; d >>= 1) ss += __shfl_down(ss, d);
    if ((tid & 63) == 0) red[tid >> 6] = ss;
    __syncthreads();
    float scale = rsqrtf((red[0] + red[1] + red[2] + red[3]) * (1.0f / DINNER) + 1e-5f);
    f32x4 w0 = *(const f32x4*)&nw[tid * 8];
    f32x4 w1 = *(const f32x4*)&nw[tid * 8 + 4];
    short8 o;
#pragma unroll
    for (int i = 0; i < 4; i++) o[i] = f2bits(v[i] * scale * w0[i]);
#pragma unroll
    for (int i = 0; i < 4; i++) o[4 + i] = f2bits(v[4 + i] * scale * w1[i]);
    *(short8*)&((short*)yb)[(size_t)t * DINNER + tid * 8] = o;
}

extern "C" void kernel_launch(void* const* d_in, const int* in_sizes, int n_in,
                              void* d_out, int out_size, void* d_ws, size_t ws_size,
                              hipStream_t stream) {
    const float* u       = (const float*)d_in[0];
    const float* W_in    = (const float*)d_in[1];
    const float* conv_w  = (const float*)d_in[2];
    const float* conv_b  = (const float*)d_in[3];
    const float* dt_bias = (const float*)d_in[4];
    const float* A_log   = (const float*)d_in[5];
    const float* Dp      = (const float*)d_in[6];
    const float* norm_w  = (const float*)d_in[7];
    const float* W_out   = (const float*)d_in[8];
    float* out = (float*)d_out;

    // Workspace layout (~105 MiB total):
    char* ws = (char*)d_ws;
    bf16* zx     = (bf16*)ws;  ws += (size_t)MTOT * N1 * 2;       // 69.2 MB
    bf16* xbc    = (bf16*)ws;  ws += (size_t)MTOT * CONVD * 2;    // 34 MB (reused as y_b)
    bf16* wout_b = (bf16*)ws;  ws += (size_t)DMODEL * DINNER * 2; // 4 MB
    float* dtb   = (float*)ws; ws += (size_t)MTOT * NH * 4;       // 1 MB
    float* td    = (float*)ws; ws += (size_t)BSZ * NCH * NH * 4;  // 16 KB
    bf16* y_b    = (bf16*)xbc;  // xbc dead after k_y; y_b written by k_norm after

    // d_out (32 MiB) doubles as scratch: u_b/win_b live during GEMM1 only;
    // st (exactly 32 MiB bf16) lives from k_cstate until k_y; GEMM2 writes out last.
    bf16* u_b   = (bf16*)d_out;                                   // 16 MB
    bf16* win_b = (bf16*)((char*)d_out + (size_t)MTOT * DMODEL * 2); // 8.25 MB
    bf16* st    = (bf16*)d_out;                                   // 32 MB (after GEMM1)

    k_cvt<<<(MTOT * DMODEL / 4 + 255) / 256, 256, 0, stream>>>(u, u_b, MTOT * DMODEL);
    k_cvt<<<(N1 * DMODEL / 4 + 255) / 256, 256, 0, stream>>>(W_in, win_b, N1 * DMODEL);
    k_cvt<<<(DMODEL * DINNER / 4 + 255) / 256, 256, 0, stream>>>(W_out, wout_b, DMODEL * DINNER);

    k_dtproj<<<MTOT, 256, 0, stream>>>(u, W_in, dt_bias, dtb);

    k_gemm_bt<bf16><<<dim3(N1 / 128, MTOT / 128), 256, 0, stream>>>(u_b, win_b, zx, N1, DMODEL);

    k_conv<<<(MTOT * CONVD / 4 + 255) / 256, 256, 0, stream>>>(zx, conv_w, conv_b, xbc);

    k_cstate<<<dim3(NH, NCH, BSZ), 256, 0, stream>>>(xbc, dtb, A_log, st, td);
    k_scan<<<(BSZ * NH * HD * DSTATE + 255) / 256, 256, 0, stream>>>(st, td);
    k_y<<<dim3(NH, NCH, BSZ), 256, 0, stream>>>(xbc, dtb, A_log, Dp, st, zx);

    k_norm<<<MTOT, 256, 0, stream>>>(zx, norm_w, y_b);

    k_gemm_bt<float><<<dim3(DMODEL / 128, MTOT / 128), 256, 0, stream>>>(y_b, wout_b, out, DMODEL, DINNER);
}

// Round 5
// 400.724 us; speedup vs baseline: 5.2956x; 1.1426x over previous
//
#include <hip/hip_runtime.h>
#include <hip/hip_bf16.h>

#define BSZ 4
#define SEQ 2048
#define DMODEL 1024
#define DINNER 2048
#define DSTATE 64
#define NH 32
#define HD 64
#define CKL 64            // chunk length
#define NCH 32            // chunks per sequence
#define CONVD 2176
#define DPROJ 4256
#define N1 4224           // GEMM1 N = DINNER + CONVD = 33*128 (dt cols handled separately)
#define MTOT 8192         // BSZ*SEQ
#define YSTR 72           // LDS row stride (bf16): 144 B, keeps 16B alignment

typedef __hip_bfloat16 bf16;
typedef __attribute__((ext_vector_type(8))) short short8;   // 8 bf16 (4 VGPRs)
typedef __attribute__((ext_vector_type(4))) short short4_;  // 8 bytes
typedef __attribute__((ext_vector_type(2))) short short2_;  // 4 bytes
typedef __attribute__((ext_vector_type(4))) float f32x4;

__device__ __forceinline__ float sigmoidf_(float x) { return 1.0f / (1.0f + __expf(-x)); }
__device__ __forceinline__ float bits2f(short s) { return __uint_as_float(((unsigned)(unsigned short)s) << 16); }
__device__ __forceinline__ short f2bits(float f) {
    bf16 h = __float2bfloat16(f);
    return *reinterpret_cast<short*>(&h);
}

__device__ __forceinline__ void gl_lds16(const bf16* g, bf16* l) {
    __builtin_amdgcn_global_load_lds((const __attribute__((address_space(1))) void*)g,
                                     (__attribute__((address_space(3))) void*)l, 16, 0, 0);
}

__device__ __forceinline__ void store_val(float* p, float v) { *p = v; }
__device__ __forceinline__ void store_val(bf16* p, float v) { *p = __float2bfloat16(v); }

// ---------------- fp32 -> bf16 convert (vectorized: 4 elems/thread; n % 4 == 0) ----------------
__global__ void k_cvt(const float* __restrict__ src, bf16* __restrict__ dst, int n) {
    int i = blockIdx.x * 256 + threadIdx.x;
    int g = i * 4;
    if (g < n) {
        f32x4 f = *(const f32x4*)&src[g];
        short4_ o;
#pragma unroll
        for (int j = 0; j < 4; j++) o[j] = f2bits(f[j]);
        *(short4_*)&dst[g] = o;
    }
}

// ---------------- bf16 MFMA GEMM: C[M][N] = A[M][K] * W[N][K]^T ----------------
// 128x128 tile, BK=64, XOR-swizzled LDS columns to keep b128 reads at the 8-way floor.
// LDS[r][cb] holds global col-block cb ^ (r&7); staging thread (row r=tid>>3, pos cb=tid&7)
// loads global block cb^(r&7) -> still one 128B segment per 8 lanes (permuted).
template <typename TOUT>
__global__ __launch_bounds__(256) void k_gemm_bt(const bf16* __restrict__ A, const bf16* __restrict__ W,
                                                 TOUT* __restrict__ C, int N, int K) {
    __shared__ __align__(16) bf16 lA[128 * 64];
    __shared__ __align__(16) bf16 lB[128 * 64];
    const int tid = threadIdx.x;
    const int lane = tid & 63, w = tid >> 6;
    const int wm = w >> 1, wn = w & 1;
    const int lr = lane & 15, lk = lane >> 4;
    const int m0 = blockIdx.y * 128, n0 = blockIdx.x * 128;

    f32x4 acc[4][4];
#pragma unroll
    for (int i = 0; i < 4; i++)
#pragma unroll
        for (int j = 0; j < 4; j++) acc[i][j] = (f32x4){0.f, 0.f, 0.f, 0.f};

    const int r = tid >> 3;                       // 0..31: row within a 32-row staging group
    const int cs = ((tid & 7) ^ (r & 7)) * 8;     // swizzled source col (bf16) within K-tile
    const bf16* ga = A + (size_t)(m0 + r) * K + cs;
    const bf16* gb = W + (size_t)(n0 + r) * K + cs;
    bf16* la0 = lA + tid * 8;                     // wave-uniform base + lane*16B
    bf16* lb0 = lB + tid * 8;
    const int sx = (lr & 7);                      // fragment-read swizzle key

    for (int kt = 0; kt < K; kt += 64) {
#pragma unroll
        for (int i = 0; i < 4; i++) {
            gl_lds16(ga + kt + (size_t)(32 * i) * K, la0 + 2048 * i);
            gl_lds16(gb + kt + (size_t)(32 * i) * K, lb0 + 2048 * i);
        }
        __syncthreads();
#pragma unroll
        for (int hh = 0; hh < 2; hh++) {
            const int cb = ((lk + 4 * hh) ^ sx) * 8;
            short8 af[4], bfr[4];
#pragma unroll
            for (int im = 0; im < 4; im++)
                af[im] = *(const short8*)&lA[(wm * 64 + im * 16 + lr) * 64 + cb];
#pragma unroll
            for (int jn = 0; jn < 4; jn++)
                bfr[jn] = *(const short8*)&lB[(wn * 64 + jn * 16 + lr) * 64 + cb];
#pragma unroll
            for (int im = 0; im < 4; im++)
#pragma unroll
                for (int jn = 0; jn < 4; jn++)
                    acc[im][jn] = __builtin_amdgcn_mfma_f32_16x16x32_bf16(af[im], bfr[jn], acc[im][jn], 0, 0, 0);
        }
        __syncthreads();
    }
#pragma unroll
    for (int im = 0; im < 4; im++) {
        int row = m0 + wm * 64 + im * 16 + lk * 4;
#pragma unroll
        for (int jn = 0; jn < 4; jn++) {
            int col = n0 + wn * 64 + jn * 16 + lr;
            TOUT* cp = C + (size_t)row * N + col;
#pragma unroll
            for (int rr = 0; rr < 4; rr++) store_val(cp + (size_t)rr * N, acc[im][jn][rr]);
        }
    }
}

// ---------------- fused: u row -> bf16 + dt projection. 8 rows per block. ----------------
__global__ __launch_bounds__(256) void k_prep(const float* __restrict__ u, const float* __restrict__ W_in,
                                              const float* __restrict__ dt_bias,
                                              bf16* __restrict__ u_b, float* __restrict__ dtb) {
    __shared__ __align__(16) float us[8 * DMODEL];
    const int t0 = blockIdx.x * 8;
    const int tid = threadIdx.x;
    const float* ur = u + (size_t)t0 * DMODEL;
    bf16* ub = u_b + (size_t)t0 * DMODEL;
#pragma unroll
    for (int i = 0; i < 8; i++) {
        int idx = (i * 256 + tid) * 4;
        f32x4 v = *(const f32x4*)&ur[idx];
        *(f32x4*)&us[idx] = v;
        short4_ o;
#pragma unroll
        for (int j = 0; j < 4; j++) o[j] = f2bits(v[j]);
        *(short4_*)&ub[idx] = o;
    }
    __syncthreads();
    const int h = tid >> 3, sub = tid & 7;
    const float* wr = W_in + (size_t)(DPROJ - NH + h) * DMODEL;
    float s[8] = {};
    for (int k = sub * 4; k < DMODEL; k += 32) {
        f32x4 w4 = *(const f32x4*)&wr[k];
#pragma unroll
        for (int rr = 0; rr < 8; rr++) {
            const float* up = &us[rr * DMODEL + k];
            s[rr] += up[0] * w4[0] + up[1] * w4[1] + up[2] * w4[2] + up[3] * w4[3];
        }
    }
#pragma unroll
    for (int rr = 0; rr < 8; rr++) {
        s[rr] += __shfl_down(s[rr], 4, 8);
        s[rr] += __shfl_down(s[rr], 2, 8);
        s[rr] += __shfl_down(s[rr], 1, 8);
    }
    if (sub == 0) {
        float bh = dt_bias[h];
#pragma unroll
        for (int rr = 0; rr < 8; rr++) {
            float x = s[rr] + bh;
            dtb[(size_t)(t0 + rr) * NH + h] = (x > 20.f) ? x : log1pf(__expf(x));
        }
    }
}

// ---------------- depthwise causal conv (width 4) + bias + SiLU — 4 channels/thread ----------------
__global__ void k_conv(const bf16* __restrict__ zx, const float* __restrict__ cw,
                       const float* __restrict__ cb, bf16* __restrict__ xbc) {
    int i = blockIdx.x * 256 + threadIdx.x;
    int g = i * 4;
    if (g >= MTOT * CONVD) return;
    int c0 = g % CONVD;
    int t = g / CONVD;
    int s = t & (SEQ - 1);
    const short* base = (const short*)(zx + (size_t)t * N1 + DINNER + c0);
    f32x4 w0 = *(const f32x4*)&cw[(c0 + 0) * 4];
    f32x4 w1 = *(const f32x4*)&cw[(c0 + 1) * 4];
    f32x4 w2 = *(const f32x4*)&cw[(c0 + 2) * 4];
    f32x4 w3 = *(const f32x4*)&cw[(c0 + 3) * 4];
    f32x4 a = *(const f32x4*)&cb[c0];
#pragma unroll
    for (int k = 0; k < 4; k++) {
        int st = s - 3 + k;
        if (st >= 0) {
            short4_ v = *(const short4_*)(base + (long)(k - 3) * N1);
            a[0] += bits2f(v[0]) * w0[k];
            a[1] += bits2f(v[1]) * w1[k];
            a[2] += bits2f(v[2]) * w2[k];
            a[3] += bits2f(v[3]) * w3[k];
        }
    }
    short4_ o;
#pragma unroll
    for (int j = 0; j < 4; j++) o[j] = f2bits(a[j] * sigmoidf_(a[j]));
    *(short4_*)&xbc[g] = o;
}

// ---------------- per-(b,c,h): chunk state S[p][n] = sum_l exp(tot-Ac[l])*dt[l]*B[l][n]*x[l][p] ------
__global__ __launch_bounds__(256) void k_cstate(const bf16* __restrict__ xbc, const float* __restrict__ dt,
                                                const float* __restrict__ A_log, bf16* __restrict__ states,
                                                float* __restrict__ totdec) {
    __shared__ __align__(16) short Bt[CKL * YSTR];   // [n][l]; reused as Ys epilogue buffer
    __shared__ __align__(16) short Xt[CKL * YSTR];   // [p][l]
    __shared__ float sf[CKL];                        // exp(tot - Ac[l]) * dt[l]
    const int h = blockIdx.x, c = blockIdx.y, b = blockIdx.z;
    const int tid = threadIdx.x;
    const int row0 = b * SEQ + c * CKL;
    const float Ah = -__expf(A_log[h]);

    if (tid < 64) {  // wave 0: dt load + inclusive scan of A*dt
        float dv = dt[(size_t)(row0 + tid) * NH + h];
        float v = Ah * dv;
#pragma unroll
        for (int d = 1; d < 64; d <<= 1) {
            float o = __shfl_up(v, d);
            if (tid >= d) v += o;
        }
        float tot = __shfl(v, 63);
        sf[tid] = __expf(tot - v) * dv;
        if (tid == 63) totdec[(b * NCH + c) * NH + h] = tot;
    }
    {
        const int n0 = (tid & 15) * 4;
#pragma unroll
        for (int it = 0; it < 4; it++) {
            int l = it * 16 + (tid >> 4);
            const short* rp = (const short*)(xbc + (size_t)(row0 + l) * CONVD);
            short4_ b4 = *(const short4_*)&rp[DINNER + n0];
            short4_ x4 = *(const short4_*)&rp[h * HD + n0];
#pragma unroll
            for (int j = 0; j < 4; j++) {
                Bt[(n0 + j) * YSTR + l] = b4[j];
                Xt[(n0 + j) * YSTR + l] = x4[j];
            }
        }
    }
    __syncthreads();
    {   // scale Bt[n][l] by sf[l] in place
        const int l0 = (tid & 15) * 4;
        f32x4 f = *(const f32x4*)&sf[l0];
#pragma unroll
        for (int it = 0; it < 4; it++) {
            int n = it * 16 + (tid >> 4);
            short* p = &Bt[n * YSTR + l0];
            short4_ v = *(short4_*)p;
#pragma unroll
            for (int j = 0; j < 4; j++) v[j] = f2bits(bits2f(v[j]) * f[j]);
            *(short4_*)p = v;
        }
    }
    __syncthreads();
    const int lane = tid & 63, w = tid >> 6;
    const int lr = lane & 15, lk = lane >> 4;
    short8 af0 = *(const short8*)&Xt[(16 * w + lr) * YSTR + lk * 8];
    short8 af1 = *(const short8*)&Xt[(16 * w + lr) * YSTR + 32 + lk * 8];
    f32x4 acc[4];
#pragma unroll
    for (int t = 0; t < 4; t++) {
        short8 b0 = *(const short8*)&Bt[(16 * t + lr) * YSTR + lk * 8];
        short8 b1 = *(const short8*)&Bt[(16 * t + lr) * YSTR + 32 + lk * 8];
        acc[t] = __builtin_amdgcn_mfma_f32_16x16x32_bf16(af0, b0, (f32x4){0.f, 0.f, 0.f, 0.f}, 0, 0, 0);
        acc[t] = __builtin_amdgcn_mfma_f32_16x16x32_bf16(af1, b1, acc[t], 0, 0, 0);
    }
    __syncthreads();   // all waves done reading Bt/Xt
    short* Ys = Bt;    // reuse: [p][n]
#pragma unroll
    for (int t = 0; t < 4; t++) {
        int n = 16 * t + lr;
#pragma unroll
        for (int rr = 0; rr < 4; rr++)
            Ys[(16 * w + lk * 4 + rr) * YSTR + n] = f2bits(acc[t][rr]);
    }
    // within-wave rows -> no barrier; coalesced 32B/lane store
    short* sp = (short*)(states + (((size_t)(b * NCH + c) * NH + h) << 12));
    {
        int p = 16 * w + (lane >> 2);
        int n0 = (lane & 3) * 16;
        short8 a0 = *(const short8*)&Ys[p * YSTR + n0];
        short8 a1 = *(const short8*)&Ys[p * YSTR + n0 + 8];
        *(short8*)&sp[p * 64 + n0] = a0;
        *(short8*)&sp[p * 64 + n0 + 8] = a1;
    }
}

// ---------------- inter-chunk scan: 2 elems (4B) per lane ----------------
__global__ void k_scan(bf16* __restrict__ states, const float* __restrict__ totdec) {
    int i = blockIdx.x * 256 + threadIdx.x;
    if (i >= BSZ * NH * 2048) return;
    int pn = (i & 2047) * 2;
    int h = (i >> 11) & 31;
    int b = i >> 16;
    float s0 = 0.f, s1 = 0.f;
    size_t strideC = (size_t)NH << 12;
    size_t off = (((size_t)(b * NCH) * NH + h) << 12) + pn;
    const float* tdp = totdec + (b * NCH) * NH + h;
    for (int c = 0; c < NCH; c++) {
        short2_ v = *(short2_*)&states[off];
        short2_ o; o[0] = f2bits(s0); o[1] = f2bits(s1);
        *(short2_*)&states[off] = o;
        float e = __expf(tdp[c * NH]);
        s0 = s0 * e + bits2f(v[0]);
        s1 = s1 * e + bits2f(v[1]);
        off += strideC;
    }
}

// ---------------- per-(b,c,h): Y = Y_diag + Y_off + D*x, gate with silu(z) — MFMA ----------
__global__ __launch_bounds__(256) void k_y(const bf16* __restrict__ xbc, const float* __restrict__ dt,
                                           const float* __restrict__ A_log, const float* __restrict__ Dp,
                                           const bf16* __restrict__ states, bf16* __restrict__ zx) {
    __shared__ __align__(16) short Cs[CKL * YSTR];   // reused as Ys epilogue buffer
    __shared__ __align__(16) short Bs[CKL * YSTR];
    __shared__ __align__(16) short Ss[CKL * YSTR];   // S0[p][n]
    __shared__ __align__(16) short Xt[CKL * YSTR];   // X transposed: [p][s]
    __shared__ __align__(16) short Gs[4 * 16 * YSTR];// per-wave G tiles [l_local][s]
    __shared__ float sdt[CKL], sAc[CKL];
    const int h = blockIdx.x, c = blockIdx.y, b = blockIdx.z;
    const int tid = threadIdx.x;
    const int row0 = b * SEQ + c * CKL;
    const float Ah = -__expf(A_log[h]);
    const float Dh = Dp[h];

    if (tid < 64) {
        float dv = dt[(size_t)(row0 + tid) * NH + h];
        sdt[tid] = dv;
        float v = Ah * dv;
#pragma unroll
        for (int d = 1; d < 64; d <<= 1) {
            float o = __shfl_up(v, d);
            if (tid >= d) v += o;
        }
        sAc[tid] = v;
    }
    const short* spg = (const short*)(states + (((size_t)(b * NCH + c) * NH + h) << 12));
    {
        const int n0 = (tid & 15) * 4;
#pragma unroll
        for (int it = 0; it < 4; it++) {
            int l = it * 16 + (tid >> 4);
            const short* rp = (const short*)(xbc + (size_t)(row0 + l) * CONVD);
            *(short4_*)&Cs[l * YSTR + n0] = *(const short4_*)&rp[DINNER + DSTATE + n0];
            *(short4_*)&Bs[l * YSTR + n0] = *(const short4_*)&rp[DINNER + n0];
            *(short4_*)&Ss[l * YSTR + n0] = *(const short4_*)&spg[l * 64 + n0];
            short4_ x4 = *(const short4_*)&rp[h * HD + n0];
#pragma unroll
            for (int j = 0; j < 4; j++) Xt[(n0 + j) * YSTR + l] = x4[j];
        }
    }
    __syncthreads();

    const int lane = tid & 63, w = tid >> 6;
    const int lr = lane & 15, lk = lane >> 4;
    short* gw = Gs + w * 16 * YSTR;

    short8 cf0 = *(const short8*)&Cs[(16 * w + lr) * YSTR + lk * 8];
    short8 cf1 = *(const short8*)&Cs[(16 * w + lr) * YSTR + 32 + lk * 8];

    // P1: Y_off = C * S0^T
    f32x4 acc[4];
#pragma unroll
    for (int t = 0; t < 4; t++) {
        short8 s0 = *(const short8*)&Ss[(16 * t + lr) * YSTR + lk * 8];
        short8 s1 = *(const short8*)&Ss[(16 * t + lr) * YSTR + 32 + lk * 8];
        acc[t] = __builtin_amdgcn_mfma_f32_16x16x32_bf16(cf0, s0, (f32x4){0.f, 0.f, 0.f, 0.f}, 0, 0, 0);
        acc[t] = __builtin_amdgcn_mfma_f32_16x16x32_bf16(cf1, s1, acc[t], 0, 0, 0);
    }
    float sAcl[4], el[4];
#pragma unroll
    for (int rr = 0; rr < 4; rr++) {
        sAcl[rr] = sAc[16 * w + lk * 4 + rr];
        el[rr] = __expf(sAcl[rr]);
    }
#pragma unroll
    for (int t = 0; t < 4; t++)
#pragma unroll
        for (int rr = 0; rr < 4; rr++) acc[t][rr] *= el[rr];

    // P2: G = C * B^T, mask/decay, round-trip wave-private LDS (C/D -> A layout)
#pragma unroll
    for (int t = 0; t < 4; t++) {
        short8 b0 = *(const short8*)&Bs[(16 * t + lr) * YSTR + lk * 8];
        short8 b1 = *(const short8*)&Bs[(16 * t + lr) * YSTR + 32 + lk * 8];
        f32x4 g = __builtin_amdgcn_mfma_f32_16x16x32_bf16(cf0, b0, (f32x4){0.f, 0.f, 0.f, 0.f}, 0, 0, 0);
        g = __builtin_amdgcn_mfma_f32_16x16x32_bf16(cf1, b1, g, 0, 0, 0);
        int s = 16 * t + lr;
        float sAcs = sAc[s], dts = sdt[s];
#pragma unroll
        for (int rr = 0; rr < 4; rr++) {
            int l = 16 * w + lk * 4 + rr;
            float v = (s <= l) ? g[rr] * __expf(sAcl[rr] - sAcs) * dts : 0.f;
            gw[(lk * 4 + rr) * YSTR + s] = f2bits(v);
        }
    }
    // P3: acc += G * X
    short8 gf0 = *(const short8*)&gw[lr * YSTR + lk * 8];
    short8 gf1 = *(const short8*)&gw[lr * YSTR + 32 + lk * 8];
#pragma unroll
    for (int t = 0; t < 4; t++) {
        short8 x0 = *(const short8*)&Xt[(16 * t + lr) * YSTR + lk * 8];
        short8 x1 = *(const short8*)&Xt[(16 * t + lr) * YSTR + 32 + lk * 8];
        acc[t] = __builtin_amdgcn_mfma_f32_16x16x32_bf16(gf0, x0, acc[t], 0, 0, 0);
        acc[t] = __builtin_amdgcn_mfma_f32_16x16x32_bf16(gf1, x1, acc[t], 0, 0, 0);
    }
    __syncthreads();   // all waves done with Cs (frag loads) before reuse
    short* Ys = Cs;    // reuse: [l][p]
#pragma unroll
    for (int t = 0; t < 4; t++) {
        int p = 16 * t + lr;
#pragma unroll
        for (int rr = 0; rr < 4; rr++) {
            int l = 16 * w + lk * 4 + rr;
            float y = acc[t][rr] + Dh * bits2f(Xt[p * YSTR + l]);
            Ys[l * YSTR + p] = f2bits(y);
        }
    }
    // within-wave rows; coalesced 32B/lane z-gate update
    {
        int l = 16 * w + (lane >> 2);
        int p0 = (lane & 3) * 16;
        short8 y0 = *(const short8*)&Ys[l * YSTR + p0];
        short8 y1 = *(const short8*)&Ys[l * YSTR + p0 + 8];
        short* zp = (short*)(zx + (size_t)(row0 + l) * N1 + h * HD + p0);
        short8 z0 = *(const short8*)zp;
        short8 z1 = *(const short8*)(zp + 8);
        short8 o0, o1;
#pragma unroll
        for (int j = 0; j < 8; j++) {
            float z = bits2f(z0[j]);
            o0[j] = f2bits(bits2f(y0[j]) * (z * sigmoidf_(z)));
        }
#pragma unroll
        for (int j = 0; j < 8; j++) {
            float z = bits2f(z1[j]);
            o1[j] = f2bits(bits2f(y1[j]) * (z * sigmoidf_(z)));
        }
        *(short8*)zp = o0;
        *(short8*)(zp + 8) = o1;
    }
}

// ---------------- RMSNorm over DINNER + bf16 cast for GEMM2 (contiguous 16B/lane) ----------------
__global__ __launch_bounds__(256) void k_norm(const bf16* __restrict__ zx, const float* __restrict__ nw,
                                              bf16* __restrict__ yb) {
    __shared__ float red[4];
    int t = blockIdx.x, tid = threadIdx.x;
    const short* row = (const short*)(zx + (size_t)t * N1);
    short8 v8 = *(const short8*)&row[tid * 8];
    float v[8];
    float ss = 0.f;
#pragma unroll
    for (int i = 0; i < 8; i++) {
        v[i] = bits2f(v8[i]);
        ss += v[i] * v[i];
    }
#pragma unroll
    for (int d = 32; d > 0; d >>= 1) ss += __shfl_down(ss, d);
    if ((tid & 63) == 0) red[tid >> 6] = ss;
    __syncthreads();
    float scale = rsqrtf((red[0] + red[1] + red[2] + red[3]) * (1.0f / DINNER) + 1e-5f);
    f32x4 w0 = *(const f32x4*)&nw[tid * 8];
    f32x4 w1 = *(const f32x4*)&nw[tid * 8 + 4];
    short8 o;
#pragma unroll
    for (int i = 0; i < 4; i++) o[i] = f2bits(v[i] * scale * w0[i]);
#pragma unroll
    for (int i = 0; i < 4; i++) o[4 + i] = f2bits(v[4 + i] * scale * w1[i]);
    *(short8*)&((short*)yb)[(size_t)t * DINNER + tid * 8] = o;
}

extern "C" void kernel_launch(void* const* d_in, const int* in_sizes, int n_in,
                              void* d_out, int out_size, void* d_ws, size_t ws_size,
                              hipStream_t stream) {
    const float* u       = (const float*)d_in[0];
    const float* W_in    = (const float*)d_in[1];
    const float* conv_w  = (const float*)d_in[2];
    const float* conv_b  = (const float*)d_in[3];
    const float* dt_bias = (const float*)d_in[4];
    const float* A_log   = (const float*)d_in[5];
    const float* Dp      = (const float*)d_in[6];
    const float* norm_w  = (const float*)d_in[7];
    const float* W_out   = (const float*)d_in[8];
    float* out = (float*)d_out;

    // Workspace layout (~105 MiB total):
    char* ws = (char*)d_ws;
    bf16* zx     = (bf16*)ws;  ws += (size_t)MTOT * N1 * 2;       // 69.2 MB
    bf16* xbc    = (bf16*)ws;  ws += (size_t)MTOT * CONVD * 2;    // 34 MB (reused as y_b)
    bf16* wout_b = (bf16*)ws;  ws += (size_t)DMODEL * DINNER * 2; // 4 MB
    float* dtb   = (float*)ws; ws += (size_t)MTOT * NH * 4;       // 1 MB
    float* td    = (float*)ws; ws += (size_t)BSZ * NCH * NH * 4;  // 16 KB
    bf16* y_b    = (bf16*)xbc;  // xbc dead after k_y; y_b written by k_norm after

    // d_out (32 MiB) doubles as scratch: u_b/win_b live during GEMM1 only;
    // st (exactly 32 MiB bf16) lives from k_cstate until k_y; GEMM2 writes out last.
    bf16* u_b   = (bf16*)d_out;                                   // 16 MB
    bf16* win_b = (bf16*)((char*)d_out + (size_t)MTOT * DMODEL * 2); // 8.25 MB
    bf16* st    = (bf16*)d_out;                                   // 32 MB (after GEMM1)

    k_prep<<<MTOT / 8, 256, 0, stream>>>(u, W_in, dt_bias, u_b, dtb);
    k_cvt<<<(N1 * DMODEL / 4 + 255) / 256, 256, 0, stream>>>(W_in, win_b, N1 * DMODEL);
    k_cvt<<<(DMODEL * DINNER / 4 + 255) / 256, 256, 0, stream>>>(W_out, wout_b, DMODEL * DINNER);

    k_gemm_bt<bf16><<<dim3(N1 / 128, MTOT / 128), 256, 0, stream>>>(u_b, win_b, zx, N1, DMODEL);

    k_conv<<<(MTOT * CONVD / 4 + 255) / 256, 256, 0, stream>>>(zx, conv_w, conv_b, xbc);

    k_cstate<<<dim3(NH, NCH, BSZ), 256, 0, stream>>>(xbc, dtb, A_log, st, td);
    k_scan<<<(BSZ * NH * 2048 + 255) / 256, 256, 0, stream>>>(st, td);
    k_y<<<dim3(NH, NCH, BSZ), 256, 0, stream>>>(xbc, dtb, A_log, Dp, st, zx);

    k_norm<<<MTOT, 256, 0, stream>>>(zx, norm_w, y_b);

    k_gemm_bt<float><<<dim3(DMODEL / 128, MTOT / 128), 256, 0, stream>>>(y_b, wout_b, out, DMODEL, DINNER);
}